// Round 6
// baseline (215.937 us; speedup 1.0000x reference)
//
#include <hip/hip_runtime.h>
#include <math.h>

#define Hh 128
#define Ww 128
#define HW (128*128)
#define CIN_OFF 196
#define COFF 432

typedef _Float16 half8 __attribute__((ext_vector_type(8)));
typedef _Float16 half2v __attribute__((ext_vector_type(2)));
typedef float f32x4 __attribute__((ext_vector_type(4)));

static __device__ __forceinline__ half8 splat8(float v) {
  _Float16 h = (_Float16)v;
  half8 r = {h, h, h, h, h, h, h, h};
  return r;
}

// ---------------- kernel 0a: dc_weight [64][128][9] fp32 -> wH[co][k*128+ci] fp16 --------
__global__ __launch_bounds__(256) void k_prep_dcw(const float* __restrict__ dcw,
                                                  _Float16* __restrict__ wH) {
  int idx = blockIdx.x * 256 + threadIdx.x;   // 64*1152 = 73728
  if (idx < 64 * 1152) {
    int co = idx / 1152;
    int j  = idx - co * 1152;
    int k  = j >> 7;
    int ci = j & 127;
    wH[idx] = (_Float16)dcw[(co * 128 + ci) * 9 + k];
  }
}

// ---------------- kernel 0b: w_off [432][196][9] fp32 -> Bp[448][9*224] fp16 --------------
__global__ __launch_bounds__(256) void k_prep_w(const float* __restrict__ w_off,
                                                _Float16* __restrict__ Bp) {
  int idx = blockIdx.x * 256 + threadIdx.x;   // 448*2016 = 903168
  if (idx >= 448 * 2016) return;
  int n = idx / 2016;
  int k = idx - n * 2016;
  int t = k / 224;
  int ci = k - t * 224;
  float v = 0.f;
  if (n < COFF && ci < CIN_OFF) v = w_off[((size_t)n * CIN_OFF + ci) * 9 + t];
  Bp[idx] = (_Float16)v;
}

// ---------------- kernel 0c: features -> per-group channel-last fp16 ---------------------
// featT[b][g][hw][8c], g 0..15 (g<8 = feat_prop, g>=8 = feat_n2).
__global__ __launch_bounds__(256) void k_prep_feat(const float* __restrict__ fp,
                                                   const float* __restrict__ fn2,
                                                   _Float16* __restrict__ featT) {
  const int t = blockIdx.x * 256 + threadIdx.x;   // 0..32767 = b*HW+hw
  const int b = t >> 14;
  const int hw = t & 16383;
#pragma unroll
  for (int g = 0; g < 16; ++g) {
    const float* src = (g < 8) ? fp : fn2;
    const int ch0 = (g & 7) * 8;
    half8 v;
#pragma unroll
    for (int c = 0; c < 8; ++c)
      v[c] = (_Float16)src[(size_t)(b * 64 + ch0 + c) * HW + hw];
    *(half8*)(featT + (((size_t)(b * 16 + g)) * HW + hw) * 8) = v;
  }
}

// ---------------- kernel 1: offset conv as fp16 MFMA implicit GEMM ------------------------
// grid (128 h, 2 b), block 512 (8 waves: 2M x 4N). M=128 px, N=448, K=9x224.
// Single-buffered LDS; tap loop unrolled x3 so the compiler pipelines B-loads
// (L2 ~250cy) under MFMA (28 x ~5cy per tap).  launch_bounds caps VGPR at 256.
__global__ __launch_bounds__(512, 2) void k_offconv_mfma(
    const float* __restrict__ extra, const float* __restrict__ f1, const float* __restrict__ f2,
    const _Float16* __restrict__ Bp, const float* __restrict__ b_off,
    float* __restrict__ off_pm, _Float16* __restrict__ mask_pm) {
  __shared__ __align__(16) _Float16 xs[3][132][40];  // [row][px(+1 shift)][ci chunk pad 40]
  const int h    = blockIdx.x;
  const int b    = blockIdx.y;
  const int tid  = (int)threadIdx.x;
  const int lane = tid & 63;
  const int wid  = tid >> 6;
  const int wm   = wid >> 2;      // 0..1
  const int wn   = wid & 3;       // 0..3
  const int m_base = wm * 64;
  const int n_base = wn * 112;
  const int l15 = lane & 15;
  const int l4  = lane >> 4;

  f32x4 acc[4][7];
#pragma unroll
  for (int i = 0; i < 4; ++i)
#pragma unroll
    for (int j = 0; j < 7; ++j) acc[i][j] = (f32x4){0.f, 0.f, 0.f, 0.f};

  // zero the p=0 and p=129 edge columns ONCE (image cols -1 and 128)
  if (tid < 240) {
    const int r   = tid / 80;
    const int rem = tid - r * 80;
    const int p   = (rem >= 40) ? 129 : 0;
    const int ci  = (rem >= 40) ? (rem - 40) : rem;
    xs[r][p][ci] = (_Float16)0.f;
  }

#pragma unroll 1
  for (int chunk = 0; chunk < 7; ++chunk) {
    const int ci0 = chunk * 32;
    __syncthreads();
    // stage 32 ci x 3 rows x 128 px, fp32 -> fp16, transposed to [row][px][ci]
#pragma unroll
    for (int it = 0; it < 3; ++it) {
      const int tt = tid + it * 512;       // 0..1535
      const int p2 = tt & 15;              // ci pair index
      const int r  = (tt >> 4) % 3;
      const int q  = tt / 48;              // 0..31 (4-px quad)
      const int gh = h - 1 + r;
      const int ci_a = ci0 + 2 * p2;
      float4 va = {0.f, 0.f, 0.f, 0.f}, vb = va;
      if ((unsigned)gh < (unsigned)Hh) {
        if (ci_a < CIN_OFF) {
          const float* xp = (ci_a < 192) ? extra + (size_t)(b * 192 + ci_a) * HW
                          : (ci_a < 194) ? f1 + (size_t)(b * 2 + (ci_a - 192)) * HW
                                         : f2 + (size_t)(b * 2 + (ci_a - 194)) * HW;
          va = *(const float4*)(xp + gh * Ww + 4 * q);
        }
        if (ci_a + 1 < CIN_OFF) {
          const int cb = ci_a + 1;
          const float* xp = (cb < 192) ? extra + (size_t)(b * 192 + cb) * HW
                          : (cb < 194) ? f1 + (size_t)(b * 2 + (cb - 192)) * HW
                                       : f2 + (size_t)(b * 2 + (cb - 194)) * HW;
          vb = *(const float4*)(xp + gh * Ww + 4 * q);
        }
      }
      const float av[4] = {va.x, va.y, va.z, va.w};
      const float bv[4] = {vb.x, vb.y, vb.z, vb.w};
#pragma unroll
      for (int i = 0; i < 4; ++i) {
        half2v pk;
        pk[0] = (_Float16)av[i];
        pk[1] = (_Float16)bv[i];
        *reinterpret_cast<half2v*>(&xs[r][1 + 4 * q + i][2 * p2]) = pk;
      }
    }
    __syncthreads();

    // tap loop: unroll x3 -> compiler pipelines next taps' B/A loads under MFMA
#pragma unroll 3
    for (int t = 0; t < 9; ++t) {
      const int ki = (t >= 6) ? 2 : (t >= 3 ? 1 : 0);
      const int kj = t - 3 * ki;
      half8 bf[7];
      const size_t kcol = (size_t)(t * 224 + ci0 + l4 * 8);
#pragma unroll
      for (int f = 0; f < 7; ++f)
        bf[f] = *(const half8*)(Bp + (size_t)(n_base + f * 16 + l15) * 2016 + kcol);
      half8 af[4];
#pragma unroll
      for (int mf = 0; mf < 4; ++mf)
        af[mf] = *reinterpret_cast<const half8*>(&xs[ki][m_base + mf * 16 + l15 + kj][l4 * 8]);
#pragma unroll
      for (int mf = 0; mf < 4; ++mf)
#pragma unroll
        for (int f = 0; f < 7; ++f)
          acc[mf][f] = __builtin_amdgcn_mfma_f32_16x16x32_f16(af[mf], bf[f], acc[mf][f], 0, 0, 0);
    }
  }

  // epilogue: bias + 10*tanh + flow-add -> off_pm[b][hw][288]; sigmoid -> mask_pm[b][hw][144]
  const int hw0 = h * Ww;
#pragma unroll
  for (int f = 0; f < 7; ++f) {
    const int n = n_base + f * 16 + l15;
    if (n >= COFF) continue;
    const float bias = b_off[n];
    const bool isOff = (n < 288);
    const float* fl = (n < 144) ? f1 : f2;
    const size_t fladd = (size_t)(b * 2 + ((n & 1) ^ 1)) * HW;
#pragma unroll
    for (int mf = 0; mf < 4; ++mf) {
#pragma unroll
      for (int rr = 0; rr < 4; ++rr) {
        const int m = m_base + mf * 16 + l4 * 4 + rr;
        const float v = acc[mf][f][rr] + bias;
        const int p = hw0 + m;
        if (isOff) {
          off_pm[((size_t)b * HW + p) * 288 + n] = 10.f * tanhf(v) + fl[fladd + p];
        } else {
          mask_pm[((size_t)b * HW + p) * 144 + (n - 288)] = (_Float16)(1.f / (1.f + expf(-v)));
        }
      }
    }
  }
}

// ---------------- kernel 2: modulated deformable conv, 16 px/block, MFMA phase 2 ----------
// grid (8, 128, 2), block 256 (4 waves).
__global__ __launch_bounds__(256) void k_deform2(
    const _Float16* __restrict__ featT, const float* __restrict__ off_pm,
    const _Float16* __restrict__ mask_pm, const _Float16* __restrict__ wH,
    const float* __restrict__ dcb, float* __restrict__ out) {
  __shared__ __align__(16) char smem[16 * 1160 * 2];   // 37120 B
  _Float16* sm = (_Float16*)smem;                      // sm[pix][1160], j = k*128 + (g^swz)*8 + c
  float* red = (float*)smem;                           // red[w][16][66] (aliased after sync)
  const int w0  = blockIdx.x * 16;
  const int h   = blockIdx.y;
  const int b   = blockIdx.z;
  const int tid = (int)threadIdx.x;
  const int lane = tid & 63, wid = tid >> 6;
  const int l15 = lane & 15, l4 = lane >> 4;

  // ---- phase 1: gather + bilinear + mask -> LDS ----
#pragma unroll 1
  for (int i = 0; i < 9; ++i) {
    const int p   = tid + i * 256;        // 0..2303
    const int pix = p / 144;
    const int r   = p - pix * 144;
    const int g   = r / 9;
    const int k   = r - g * 9;
    const int w   = w0 + pix;
    const int hw  = h * Ww + w;
    const float2 off = *(const float2*)(off_pm + ((size_t)b * HW + hw) * 288 + 2 * r);
    const float mk = (float)mask_pm[((size_t)b * HW + hw) * 144 + r];
    const int ki = (k >= 6) ? 2 : (k >= 3 ? 1 : 0);
    const int kj = k - 3 * ki;
    const float py = (float)(h - 1 + ki) + off.x;
    const float px = (float)(w - 1 + kj) + off.y;
    const float y0f = floorf(py), x0f = floorf(px);
    const int y0 = (int)y0f, x0 = (int)x0f;
    const float ly = py - y0f, lx = px - x0f;
    const float hy = 1.f - ly, hx = 1.f - lx;
    const int y1 = y0 + 1, x1 = x0 + 1;
    const bool vy0 = (unsigned)y0 < (unsigned)Hh, vy1 = (unsigned)y1 < (unsigned)Hh;
    const bool vx0 = (unsigned)x0 < (unsigned)Ww, vx1 = (unsigned)x1 < (unsigned)Ww;
    const float w00 = (vy0 && vx0) ? hy * hx : 0.f;
    const float w01 = (vy0 && vx1) ? hy * lx : 0.f;
    const float w10 = (vy1 && vx0) ? ly * hx : 0.f;
    const float w11 = (vy1 && vx1) ? ly * lx : 0.f;
    const int cy0 = min(max(y0, 0), Hh - 1), cy1 = min(max(y1, 0), Hh - 1);
    const int cx0 = min(max(x0, 0), Ww - 1), cx1 = min(max(x1, 0), Ww - 1);
    const _Float16* gbase = featT + ((size_t)(b * 16 + g) * HW) * 8;
    const half8 s00 = *(const half8*)(gbase + (cy0 * Ww + cx0) * 8);
    const half8 s01 = *(const half8*)(gbase + (cy0 * Ww + cx1) * 8);
    const half8 s10 = *(const half8*)(gbase + (cy1 * Ww + cx0) * 8);
    const half8 s11 = *(const half8*)(gbase + (cy1 * Ww + cx1) * 8);
    half8 v = s00 * splat8(w00) + s01 * splat8(w01) + s10 * splat8(w10) + s11 * splat8(w11);
    v = v * splat8(mk);
    const int swz = (g ^ (k & 7)) << 3;
    *(half8*)(sm + pix * 1160 + k * 128 + swz) = v;
  }
  __syncthreads();

  // ---- phase 2: MFMA, K-split over 4 waves (9 steps of K=32 each) ----
  f32x4 acc[4];
#pragma unroll
  for (int nf = 0; nf < 4; ++nf) acc[nf] = (f32x4){0.f, 0.f, 0.f, 0.f};
#pragma unroll
  for (int j = 0; j < 9; ++j) {
    const int s  = wid * 9 + j;           // global K-step 0..35
    const int k  = s >> 2;                // tap
    const int cg = s & 3;                 // 32-chunk within tap
    const int gidx = cg * 4 + l4;         // logical group of this lane's 8 ci
    const half8 af = *(const half8*)(sm + l15 * 1160 + k * 128 + ((gidx ^ (k & 7)) << 3));
    const int koff = s * 32 + l4 * 8;
#pragma unroll
    for (int nf = 0; nf < 4; ++nf) {
      const half8 bf = *(const half8*)(wH + (nf * 16 + l15) * 1152 + koff);
      acc[nf] = __builtin_amdgcn_mfma_f32_16x16x32_f16(af, bf, acc[nf], 0, 0, 0);
    }
  }
  __syncthreads();   // done reading sm; alias as red
#pragma unroll
  for (int nf = 0; nf < 4; ++nf)
#pragma unroll
    for (int rr = 0; rr < 4; ++rr)
      red[(wid * 16 + l4 * 4 + rr) * 66 + nf * 16 + l15] = acc[nf][rr];
  __syncthreads();

  // ---- reduce 4 partials + bias, coalesced store ----
  const int m  = tid & 15;
  const int ng = tid >> 4;                // 0..15
#pragma unroll
  for (int i = 0; i < 4; ++i) {
    const int n = ng + 16 * i;
    float val = red[(0 * 16 + m) * 66 + n] + red[(1 * 16 + m) * 66 + n] +
                red[(2 * 16 + m) * 66 + n] + red[(3 * 16 + m) * 66 + n];
    out[(size_t)(b * 64 + n) * HW + h * Ww + w0 + m] = val + dcb[n];
  }
}

extern "C" void kernel_launch(void* const* d_in, const int* in_sizes, int n_in,
                              void* d_out, int out_size, void* d_ws, size_t ws_size,
                              hipStream_t stream) {
  const float* extra = (const float*)d_in[0];
  const float* f1    = (const float*)d_in[1];
  const float* f2    = (const float*)d_in[2];
  const float* fp    = (const float*)d_in[3];
  const float* fn2   = (const float*)d_in[4];
  const float* w_off = (const float*)d_in[5];
  const float* b_off = (const float*)d_in[6];
  const float* dcw   = (const float*)d_in[7];
  const float* dcb   = (const float*)d_in[8];
  float* out = (float*)d_out;

  // ws layout (~57.5 MB)
  float*    off_pm  = (float*)d_ws;                      // 2*HW*288 f32 = 37.7 MB
  _Float16* mask_pm = (_Float16*)(off_pm + 2 * 288 * HW);// 2*HW*144 fp16 = 9.4 MB
  _Float16* featT   = mask_pm + 2 * 144 * HW;            // 2*HW*128 fp16 = 8.4 MB
  _Float16* Bp      = featT + 2 * 128 * HW;              // 448*2016 fp16 = 1.8 MB
  _Float16* wH      = Bp + 448 * 2016;                   // 64*1152 fp16 = 0.15 MB

  hipLaunchKernelGGL(k_prep_dcw, dim3(288), dim3(256), 0, stream, dcw, wH);
  hipLaunchKernelGGL(k_prep_w, dim3((448 * 2016 + 255) / 256), dim3(256), 0, stream, w_off, Bp);
  hipLaunchKernelGGL(k_prep_feat, dim3(128), dim3(256), 0, stream, fp, fn2, featT);
  hipLaunchKernelGGL(k_offconv_mfma, dim3(128, 2), dim3(512), 0, stream,
                     extra, f1, f2, Bp, b_off, off_pm, mask_pm);
  hipLaunchKernelGGL(k_deform2, dim3(8, 128, 2), dim3(256), 0, stream,
                     featT, off_pm, mask_pm, wH, dcb, out);
}

// Round 7
// 203.085 us; speedup vs baseline: 1.0633x; 1.0633x over previous
//
#include <hip/hip_runtime.h>
#include <math.h>

#define Hh 128
#define Ww 128
#define HW (128*128)
#define CIN_OFF 196
#define COFF 432

typedef _Float16 half8 __attribute__((ext_vector_type(8)));
typedef _Float16 half4 __attribute__((ext_vector_type(4)));
typedef _Float16 half2v __attribute__((ext_vector_type(2)));
typedef float f32x4 __attribute__((ext_vector_type(4)));

static __device__ __forceinline__ half8 splat8(float v) {
  _Float16 h = (_Float16)v;
  half8 r = {h, h, h, h, h, h, h, h};
  return r;
}

// ---------------- kernel 0a: dc_weight [64][128][9] fp32 -> wH[co][k*128+ci] fp16 --------
__global__ __launch_bounds__(256) void k_prep_dcw(const float* __restrict__ dcw,
                                                  _Float16* __restrict__ wH) {
  int idx = blockIdx.x * 256 + threadIdx.x;   // 64*1152 = 73728
  if (idx < 64 * 1152) {
    int co = idx / 1152;
    int j  = idx - co * 1152;
    int k  = j >> 7;
    int ci = j & 127;
    wH[idx] = (_Float16)dcw[(co * 128 + ci) * 9 + k];
  }
}

// ---------------- kernel 0b: w_off -> BpT[s=t*6+cg][l4][n][8] + Bt[t][n][4] fp16 ---------
// BpT element (s,l4,n,c) = w_off[n][cg*32+l4*8+c][t]   (ci < 192)
// Bt  element (t,n,c)    = w_off[n][192+c][t]           (tail ci 192..195)
__global__ __launch_bounds__(256) void k_prep_w(const float* __restrict__ w_off,
                                                _Float16* __restrict__ BpT,
                                                _Float16* __restrict__ Bt) {
  int idx = blockIdx.x * 256 + threadIdx.x;
  if (idx < 774144) {                    // 54*4*448*8
    const int c  = idx & 7;
    const int n  = (idx >> 3) % 448;
    const int sl = (idx >> 3) / 448;     // 0..215
    const int l4 = sl & 3;
    const int s  = sl >> 2;              // 0..53
    const int t  = s / 6;
    const int cg = s - t * 6;
    const int ci = cg * 32 + l4 * 8 + c; // 0..191
    BpT[idx] = (_Float16)((n < COFF) ? w_off[((size_t)n * CIN_OFF + ci) * 9 + t] : 0.f);
  } else if (idx < 774144 + 16128) {     // 9*448*4
    const int j = idx - 774144;
    const int c = j & 3;
    const int n = (j >> 2) % 448;
    const int t = (j >> 2) / 448;
    Bt[j] = (_Float16)((n < COFF) ? w_off[((size_t)n * CIN_OFF + 192 + c) * 9 + t] : 0.f);
  }
}

// ---------------- kernel 0c: features -> per-group channel-last fp16 ---------------------
__global__ __launch_bounds__(256) void k_prep_feat(const float* __restrict__ fp,
                                                   const float* __restrict__ fn2,
                                                   _Float16* __restrict__ featT) {
  const int t = blockIdx.x * 256 + threadIdx.x;   // 0..32767 = b*HW+hw
  const int b = t >> 14;
  const int hw = t & 16383;
#pragma unroll
  for (int g = 0; g < 16; ++g) {
    const float* src = (g < 8) ? fp : fn2;
    const int ch0 = (g & 7) * 8;
    half8 v;
#pragma unroll
    for (int c = 0; c < 8; ++c)
      v[c] = (_Float16)src[(size_t)(b * 64 + ch0 + c) * HW + hw];
    *(half8*)(featT + (((size_t)(b * 16 + g)) * HW + hw) * 8) = v;
  }
}

// ---------------- kernel 1: offset conv, FULL-K in LDS, barrier-free MFMA loop ------------
// grid (128 h, 2 b), block 512 (8 waves: 2M x 4N). M = 128 px, N = 448, K = 9 x 196.
// LDS: smA[3][130][192] fp16 (XOR-swizzled 16B blocks) + smT[3][130][4] fp16 tail.
// One __syncthreads after staging; 63 MFMA steps with no barriers -> deep pipelining.
__global__ __launch_bounds__(512, 2) void k_offconv_mfma(
    const float* __restrict__ extra, const float* __restrict__ f1, const float* __restrict__ f2,
    const _Float16* __restrict__ BpT, const _Float16* __restrict__ Bt,
    const float* __restrict__ b_off,
    float* __restrict__ off_pm, _Float16* __restrict__ mask_pm) {
  __shared__ __align__(16) _Float16 smA[3 * 130 * 192];  // 149,760 B
  __shared__ __align__(16) _Float16 smT[3 * 130 * 4];    //   3,120 B
  const int h    = blockIdx.x;
  const int b    = blockIdx.y;
  const int tid  = (int)threadIdx.x;
  const int lane = tid & 63;
  const int wid  = tid >> 6;
  const int wm   = wid >> 2;      // 0..1
  const int wn   = wid & 3;       // 0..3
  const int m_base = wm * 64;
  const int n_base = wn * 112;
  const int l15 = lane & 15;
  const int l4  = lane >> 4;

  // ---- zero px=0 / px=129 edge columns (image cols -1 and 128) ----
  for (int z = tid; z < 588; z += 512) {     // 3 r x 2 px x 98 ci-pairs
    const int p2 = z % 98;
    const int rr = z / 98;                   // 0..5
    const int r  = (rr >= 3) ? (rr - 3) : rr;
    const int px = (rr >= 3) ? 129 : 0;
    if (p2 < 96) {
      const int ci = 2 * p2, biw = ci >> 3;
      const int sw = ((biw & 24) | ((biw & 7) ^ (px & 7))) << 3;
      *(half2v*)(smA + (r * 130 + px) * 192 + sw + (ci & 7)) = (half2v){(_Float16)0.f, (_Float16)0.f};
    } else {
      *(half2v*)(smT + (r * 130 + px) * 4 + 2 * (p2 - 96)) = (half2v){(_Float16)0.f, (_Float16)0.f};
    }
  }

  // ---- stage ALL K: 3 rows x 128 px x 196 ci, fp32 -> fp16, transposed+swizzled ----
  for (int task = tid; task < 9408; task += 512) {   // 3 r x 98 pairs x 32 q
    const int q  = task & 31;
    const int rp = task >> 5;                // 0..293
    const int p2 = rp % 98;
    const int r  = rp / 98;                  // 0..2
    const int gh = h - 1 + r;
    const int ci = 2 * p2;                   // 0..194 (both elements real)
    float4 va = {0.f, 0.f, 0.f, 0.f}, vb = va;
    if ((unsigned)gh < (unsigned)Hh) {
      const float* xpA;
      if (p2 < 96)       xpA = extra + (size_t)(b * 192 + ci) * HW;
      else if (p2 == 96) xpA = f1 + (size_t)(b * 2) * HW;
      else               xpA = f2 + (size_t)(b * 2) * HW;
      va = *(const float4*)(xpA + gh * Ww + 4 * q);
      vb = *(const float4*)(xpA + HW + gh * Ww + 4 * q);
    }
    const float av[4] = {va.x, va.y, va.z, va.w};
    const float bv[4] = {vb.x, vb.y, vb.z, vb.w};
    if (p2 < 96) {
      const int biw = ci >> 3;
#pragma unroll
      for (int i = 0; i < 4; ++i) {
        const int px = 1 + 4 * q + i;
        const int sw = ((biw & 24) | ((biw & 7) ^ (px & 7))) << 3;
        half2v pk; pk[0] = (_Float16)av[i]; pk[1] = (_Float16)bv[i];
        *(half2v*)(smA + (r * 130 + px) * 192 + sw + (ci & 7)) = pk;
      }
    } else {
      const int ct = 2 * (p2 - 96);          // 0 or 2
#pragma unroll
      for (int i = 0; i < 4; ++i) {
        const int px = 1 + 4 * q + i;
        half2v pk; pk[0] = (_Float16)av[i]; pk[1] = (_Float16)bv[i];
        *(half2v*)(smT + (r * 130 + px) * 4 + ct) = pk;
      }
    }
  }
  __syncthreads();

  // ---- barrier-free K loop: 9 taps x (6 x K32 + 1 x K16-tail) ----
  f32x4 acc[4][7];
#pragma unroll
  for (int i = 0; i < 4; ++i)
#pragma unroll
    for (int j = 0; j < 7; ++j) acc[i][j] = (f32x4){0.f, 0.f, 0.f, 0.f};

  const bool lz = (l4 == 0);
#pragma unroll 3
  for (int t = 0; t < 9; ++t) {
    const int ki = t / 3;
    const int kj = t - 3 * ki;
#pragma unroll
    for (int cg = 0; cg < 6; ++cg) {
      const int s4 = ((t * 6 + cg) * 4 + l4) * 448;
      half8 bf[7];
#pragma unroll
      for (int f = 0; f < 7; ++f)
        bf[f] = *(const half8*)(BpT + (size_t)(s4 + n_base + f * 16 + l15) * 8);
      half8 af[4];
#pragma unroll
      for (int mf = 0; mf < 4; ++mf) {
        const int px = m_base + mf * 16 + l15 + kj;
        const int bi = cg * 4 + l4;
        af[mf] = *(const half8*)(smA + (ki * 130 + px) * 192 +
                                 (((bi & 24) | ((bi & 7) ^ (px & 7))) << 3));
      }
#pragma unroll
      for (int mf = 0; mf < 4; ++mf)
#pragma unroll
        for (int f = 0; f < 7; ++f)
          acc[mf][f] = __builtin_amdgcn_mfma_f32_16x16x32_f16(af[mf], bf[f], acc[mf][f], 0, 0, 0);
    }
    // tail: ci 192..195 as a l4==0-masked K32 MFMA
    half8 aft[4];
#pragma unroll
    for (int mf = 0; mf < 4; ++mf) {
      const int px = m_base + mf * 16 + l15 + kj;
      const half4 tv = *(const half4*)(smT + (ki * 130 + px) * 4);
      half8 a = {0, 0, 0, 0, 0, 0, 0, 0};
      if (lz) { a[0] = tv[0]; a[1] = tv[1]; a[2] = tv[2]; a[3] = tv[3]; }
      aft[mf] = a;
    }
#pragma unroll
    for (int f = 0; f < 7; ++f) {
      const half4 wv = *(const half4*)(Bt + (size_t)(t * 448 + n_base + f * 16 + l15) * 4);
      half8 bb = {0, 0, 0, 0, 0, 0, 0, 0};
      if (lz) { bb[0] = wv[0]; bb[1] = wv[1]; bb[2] = wv[2]; bb[3] = wv[3]; }
#pragma unroll
      for (int mf = 0; mf < 4; ++mf)
        acc[mf][f] = __builtin_amdgcn_mfma_f32_16x16x32_f16(aft[mf], bb, acc[mf][f], 0, 0, 0);
    }
  }

  // ---- epilogue: bias + 10*tanh + flow-add -> off_pm; sigmoid -> mask_pm ----
  const int hw0 = h * Ww;
#pragma unroll
  for (int f = 0; f < 7; ++f) {
    const int n = n_base + f * 16 + l15;
    if (n >= COFF) continue;
    const float bias = b_off[n];
    const bool isOff = (n < 288);
    const float* fl = (n < 144) ? f1 : f2;
    const size_t fladd = (size_t)(b * 2 + ((n & 1) ^ 1)) * HW;
#pragma unroll
    for (int mf = 0; mf < 4; ++mf) {
#pragma unroll
      for (int rr = 0; rr < 4; ++rr) {
        const int m = m_base + mf * 16 + l4 * 4 + rr;
        const float v = acc[mf][f][rr] + bias;
        const int p = hw0 + m;
        if (isOff) {
          off_pm[((size_t)b * HW + p) * 288 + n] = 10.f * tanhf(v) + fl[fladd + p];
        } else {
          mask_pm[((size_t)b * HW + p) * 144 + (n - 288)] = (_Float16)(1.f / (1.f + expf(-v)));
        }
      }
    }
  }
}

// ---------------- kernel 2: modulated deformable conv, 16 px/block, MFMA phase 2 ----------
__global__ __launch_bounds__(256) void k_deform2(
    const _Float16* __restrict__ featT, const float* __restrict__ off_pm,
    const _Float16* __restrict__ mask_pm, const _Float16* __restrict__ wH,
    const float* __restrict__ dcb, float* __restrict__ out) {
  __shared__ __align__(16) char smem[16 * 1160 * 2];   // 37120 B
  _Float16* sm = (_Float16*)smem;                      // sm[pix][1160]
  float* red = (float*)smem;                           // red[w][16][66] (aliased after sync)
  const int w0  = blockIdx.x * 16;
  const int h   = blockIdx.y;
  const int b   = blockIdx.z;
  const int tid = (int)threadIdx.x;
  const int lane = tid & 63, wid = tid >> 6;
  const int l15 = lane & 15, l4 = lane >> 4;

#pragma unroll 1
  for (int i = 0; i < 9; ++i) {
    const int p   = tid + i * 256;        // 0..2303
    const int pix = p / 144;
    const int r   = p - pix * 144;
    const int g   = r / 9;
    const int k   = r - g * 9;
    const int w   = w0 + pix;
    const int hw  = h * Ww + w;
    const float2 off = *(const float2*)(off_pm + ((size_t)b * HW + hw) * 288 + 2 * r);
    const float mk = (float)mask_pm[((size_t)b * HW + hw) * 144 + r];
    const int ki = (k >= 6) ? 2 : (k >= 3 ? 1 : 0);
    const int kj = k - 3 * ki;
    const float py = (float)(h - 1 + ki) + off.x;
    const float px = (float)(w - 1 + kj) + off.y;
    const float y0f = floorf(py), x0f = floorf(px);
    const int y0 = (int)y0f, x0 = (int)x0f;
    const float ly = py - y0f, lx = px - x0f;
    const float hy = 1.f - ly, hx = 1.f - lx;
    const int y1 = y0 + 1, x1 = x0 + 1;
    const bool vy0 = (unsigned)y0 < (unsigned)Hh, vy1 = (unsigned)y1 < (unsigned)Hh;
    const bool vx0 = (unsigned)x0 < (unsigned)Ww, vx1 = (unsigned)x1 < (unsigned)Ww;
    const float w00 = (vy0 && vx0) ? hy * hx : 0.f;
    const float w01 = (vy0 && vx1) ? hy * lx : 0.f;
    const float w10 = (vy1 && vx0) ? ly * hx : 0.f;
    const float w11 = (vy1 && vx1) ? ly * lx : 0.f;
    const int cy0 = min(max(y0, 0), Hh - 1), cy1 = min(max(y1, 0), Hh - 1);
    const int cx0 = min(max(x0, 0), Ww - 1), cx1 = min(max(x1, 0), Ww - 1);
    const _Float16* gbase = featT + ((size_t)(b * 16 + g) * HW) * 8;
    const half8 s00 = *(const half8*)(gbase + (cy0 * Ww + cx0) * 8);
    const half8 s01 = *(const half8*)(gbase + (cy0 * Ww + cx1) * 8);
    const half8 s10 = *(const half8*)(gbase + (cy1 * Ww + cx0) * 8);
    const half8 s11 = *(const half8*)(gbase + (cy1 * Ww + cx1) * 8);
    half8 v = s00 * splat8(w00) + s01 * splat8(w01) + s10 * splat8(w10) + s11 * splat8(w11);
    v = v * splat8(mk);
    const int swz = (g ^ (k & 7)) << 3;
    *(half8*)(sm + pix * 1160 + k * 128 + swz) = v;
  }
  __syncthreads();

  f32x4 acc[4];
#pragma unroll
  for (int nf = 0; nf < 4; ++nf) acc[nf] = (f32x4){0.f, 0.f, 0.f, 0.f};
#pragma unroll
  for (int j = 0; j < 9; ++j) {
    const int s  = wid * 9 + j;
    const int k  = s >> 2;
    const int cg = s & 3;
    const int gidx = cg * 4 + l4;
    const half8 af = *(const half8*)(sm + l15 * 1160 + k * 128 + ((gidx ^ (k & 7)) << 3));
    const int koff = s * 32 + l4 * 8;
#pragma unroll
    for (int nf = 0; nf < 4; ++nf) {
      const half8 bf = *(const half8*)(wH + (nf * 16 + l15) * 1152 + koff);
      acc[nf] = __builtin_amdgcn_mfma_f32_16x16x32_f16(af, bf, acc[nf], 0, 0, 0);
    }
  }
  __syncthreads();
#pragma unroll
  for (int nf = 0; nf < 4; ++nf)
#pragma unroll
    for (int rr = 0; rr < 4; ++rr)
      red[(wid * 16 + l4 * 4 + rr) * 66 + nf * 16 + l15] = acc[nf][rr];
  __syncthreads();

  const int m  = tid & 15;
  const int ng = tid >> 4;
#pragma unroll
  for (int i = 0; i < 4; ++i) {
    const int n = ng + 16 * i;
    float val = red[(0 * 16 + m) * 66 + n] + red[(1 * 16 + m) * 66 + n] +
                red[(2 * 16 + m) * 66 + n] + red[(3 * 16 + m) * 66 + n];
    out[(size_t)(b * 64 + n) * HW + h * Ww + w0 + m] = val + dcb[n];
  }
}

extern "C" void kernel_launch(void* const* d_in, const int* in_sizes, int n_in,
                              void* d_out, int out_size, void* d_ws, size_t ws_size,
                              hipStream_t stream) {
  const float* extra = (const float*)d_in[0];
  const float* f1    = (const float*)d_in[1];
  const float* f2    = (const float*)d_in[2];
  const float* fp    = (const float*)d_in[3];
  const float* fn2   = (const float*)d_in[4];
  const float* w_off = (const float*)d_in[5];
  const float* b_off = (const float*)d_in[6];
  const float* dcw   = (const float*)d_in[7];
  const float* dcb   = (const float*)d_in[8];
  float* out = (float*)d_out;

  // ws layout (~57.3 MB)
  float*    off_pm  = (float*)d_ws;                      // 2*HW*288 f32
  _Float16* mask_pm = (_Float16*)(off_pm + 2 * 288 * HW);// 2*HW*144 fp16
  _Float16* featT   = mask_pm + 2 * 144 * HW;            // 2*16*HW*8 fp16
  _Float16* BpT     = featT + 2 * 128 * HW;              // 774144 fp16
  _Float16* Bt      = BpT + 774144;                      // 16128 fp16
  _Float16* wH      = Bt + 16128;                        // 73728 fp16

  hipLaunchKernelGGL(k_prep_dcw, dim3(288), dim3(256), 0, stream, dcw, wH);
  hipLaunchKernelGGL(k_prep_w, dim3((774144 + 16128 + 255) / 256), dim3(256), 0, stream,
                     w_off, BpT, Bt);
  hipLaunchKernelGGL(k_prep_feat, dim3(128), dim3(256), 0, stream, fp, fn2, featT);
  hipLaunchKernelGGL(k_offconv_mfma, dim3(128, 2), dim3(512), 0, stream,
                     extra, f1, f2, BpT, Bt, b_off, off_pm, mask_pm);
  hipLaunchKernelGGL(k_deform2, dim3(8, 128, 2), dim3(256), 0, stream,
                     featT, off_pm, mask_pm, wH, dcb, out);
}

// Round 8
// 190.562 us; speedup vs baseline: 1.1332x; 1.0657x over previous
//
#include <hip/hip_runtime.h>
#include <math.h>

#define Hh 128
#define Ww 128
#define HW (128*128)
#define CIN_OFF 196
#define COFF 432

typedef _Float16 half8 __attribute__((ext_vector_type(8)));
typedef _Float16 half4 __attribute__((ext_vector_type(4)));
typedef _Float16 half2v __attribute__((ext_vector_type(2)));
typedef float f32x4 __attribute__((ext_vector_type(4)));

static __device__ __forceinline__ half8 splat8(float v) {
  _Float16 h = (_Float16)v;
  half8 r = {h, h, h, h, h, h, h, h};
  return r;
}

// ---------------- kernel 0a: dc_weight [64][128][9] fp32 -> wH[co][k*128+ci] fp16 --------
__global__ __launch_bounds__(256) void k_prep_dcw(const float* __restrict__ dcw,
                                                  _Float16* __restrict__ wH) {
  int idx = blockIdx.x * 256 + threadIdx.x;   // 64*1152 = 73728
  if (idx < 64 * 1152) {
    int co = idx / 1152;
    int j  = idx - co * 1152;
    int k  = j >> 7;
    int ci = j & 127;
    wH[idx] = (_Float16)dcw[(co * 128 + ci) * 9 + k];
  }
}

// ---------------- kernel 0b: w_off -> BpT[s=t*6+cg][l4][n<448][8] + Bt[t][n][4] fp16 ------
__global__ __launch_bounds__(256) void k_prep_w(const float* __restrict__ w_off,
                                                _Float16* __restrict__ BpT,
                                                _Float16* __restrict__ Bt) {
  int idx = blockIdx.x * 256 + threadIdx.x;
  if (idx < 774144) {                    // 54*4*448*8
    const int c  = idx & 7;
    const int n  = (idx >> 3) % 448;
    const int sl = (idx >> 3) / 448;     // 0..215
    const int l4 = sl & 3;
    const int s  = sl >> 2;              // 0..53
    const int t  = s / 6;
    const int cg = s - t * 6;
    const int ci = cg * 32 + l4 * 8 + c; // 0..191
    BpT[idx] = (_Float16)((n < COFF) ? w_off[((size_t)n * CIN_OFF + ci) * 9 + t] : 0.f);
  } else if (idx < 774144 + 16128) {     // 9*448*4
    const int j = idx - 774144;
    const int c = j & 3;
    const int n = (j >> 2) % 448;
    const int t = (j >> 2) / 448;
    Bt[j] = (_Float16)((n < COFF) ? w_off[((size_t)n * CIN_OFF + 192 + c) * 9 + t] : 0.f);
  }
}

// ---------------- kernel 0c: features -> per-group channel-last fp16 ---------------------
__global__ __launch_bounds__(256) void k_prep_feat(const float* __restrict__ fp,
                                                   const float* __restrict__ fn2,
                                                   _Float16* __restrict__ featT) {
  const int t = blockIdx.x * 256 + threadIdx.x;   // 0..32767 = b*HW+hw
  const int b = t >> 14;
  const int hw = t & 16383;
#pragma unroll
  for (int g = 0; g < 16; ++g) {
    const float* src = (g < 8) ? fp : fn2;
    const int ch0 = (g & 7) * 8;
    half8 v;
#pragma unroll
    for (int c = 0; c < 8; ++c)
      v[c] = (_Float16)src[(size_t)(b * 64 + ch0 + c) * HW + hw];
    *(half8*)(featT + (((size_t)(b * 16 + g)) * HW + hw) * 8) = v;
  }
}

// ---------------- kernel 1: offset conv, FULL-K LDS, 16 waves, barrier-free K loop --------
// grid (128 h, 2 b), block 1024 (16 waves: 4M x 4N). Per wave: 32 px x 112 n.
// LDS: smA[3][130][192] fp16 XOR-swizzled (16B slots) + smT[3][130][4] tail.
// Staging lane map: ci-pair in lane[3:0], px-quad in lane[5:4] -> conflict-free LDS writes
// and 16-line-coalesced global loads. One __syncthreads total.
__global__ __launch_bounds__(1024, 4) void k_offconv_mfma(
    const float* __restrict__ extra, const float* __restrict__ f1, const float* __restrict__ f2,
    const _Float16* __restrict__ BpT, const _Float16* __restrict__ Bt,
    const float* __restrict__ b_off,
    float* __restrict__ off_pm, _Float16* __restrict__ mask_pm) {
  __shared__ __align__(16) _Float16 smA[3 * 130 * 192];  // 149,760 B
  __shared__ __align__(16) _Float16 smT[3 * 130 * 4];    //   3,120 B
  const int h    = blockIdx.x;
  const int b    = blockIdx.y;
  const int tid  = (int)threadIdx.x;
  const int lane = tid & 63;
  const int wid  = tid >> 6;      // 0..15
  const int wm   = wid >> 2;      // 0..3  (M-wave)
  const int wn   = wid & 3;       // 0..3  (N-wave)
  const int m_base = wm * 32;
  const int n_base = wn * 112;
  const int l15 = lane & 15;
  const int l4  = lane >> 4;

  // ---- zero px=0 / px=129 edge columns (image cols -1 and 128) ----
  if (tid < 588) {     // 3 r x 2 px x 98 ci-pairs
    const int p2 = tid % 98;
    const int rr = tid / 98;                 // 0..5
    const int r  = (rr >= 3) ? (rr - 3) : rr;
    const int px = (rr >= 3) ? 129 : 0;
    if (p2 < 96) {
      const int ci = 2 * p2, biw = ci >> 3;
      const int sw = ((biw & 24) | ((biw & 7) ^ (px & 7))) << 3;
      *(half2v*)(smA + (r * 130 + px) * 192 + sw + (ci & 7)) = (half2v){(_Float16)0.f, (_Float16)0.f};
    } else {
      *(half2v*)(smT + (r * 130 + px) * 4 + 2 * (p2 - 96)) = (half2v){(_Float16)0.f, (_Float16)0.f};
    }
  }

  // ---- main staging: 3 r x 96 ci-pairs x 32 q = 9216 tasks = 9 x 1024 ----
  // lane map: p2a = lane[3:0] (ci pair), qa = lane[5:4] (px quad) -> coalesced loads,
  // conflict-free swizzled LDS writes (2 lanes/bank).
#pragma unroll 1
  for (int j = 0; j < 9; ++j) {
    const int J   = tid + 1024 * j;
    const int p2a = J & 15;
    const int qa  = (J >> 4) & 3;
    const int R   = J >> 6;                  // wave-uniform
    const int r   = R / 48;
    const int rem = R - 48 * r;
    const int qh  = rem & 7;
    const int p2h = rem >> 3;                // 0..5
    const int q   = qa + 4 * qh;             // 0..31
    const int p2  = p2a + 16 * p2h;          // 0..95
    const int ci  = 2 * p2;
    const int gh  = h - 1 + r;
    float4 va = {0.f, 0.f, 0.f, 0.f}, vb = va;
    if ((unsigned)gh < (unsigned)Hh) {
      const float* xp = extra + (size_t)(b * 192 + ci) * HW + gh * Ww + 4 * q;
      va = *(const float4*)xp;
      vb = *(const float4*)(xp + HW);
    }
    const float av[4] = {va.x, va.y, va.z, va.w};
    const float bv[4] = {vb.x, vb.y, vb.z, vb.w};
    const int biw = p2 >> 2;
#pragma unroll
    for (int i = 0; i < 4; ++i) {
      const int px = 1 + 4 * q + i;
      const int sw = ((biw & 24) | ((biw & 7) ^ (px & 7))) << 3;
      half2v pk; pk[0] = (_Float16)av[i]; pk[1] = (_Float16)bv[i];
      *(half2v*)(smA + (r * 130 + px) * 192 + sw + (ci & 7)) = pk;
    }
  }
  // ---- tail staging: ci 192..195 (f1, f2), 3 r x 2 x 32 q = 192 tasks ----
  if (tid < 192) {
    const int q   = tid & 31;
    const int p2t = (tid >> 5) & 1;
    const int r   = tid >> 6;
    const int gh  = h - 1 + r;
    float4 va = {0.f, 0.f, 0.f, 0.f}, vb = va;
    if ((unsigned)gh < (unsigned)Hh) {
      const float* xp = (p2t ? f2 : f1) + (size_t)(b * 2) * HW + gh * Ww + 4 * q;
      va = *(const float4*)xp;
      vb = *(const float4*)(xp + HW);
    }
    const float av[4] = {va.x, va.y, va.z, va.w};
    const float bv[4] = {vb.x, vb.y, vb.z, vb.w};
#pragma unroll
    for (int i = 0; i < 4; ++i) {
      const int px = 1 + 4 * q + i;
      half2v pk; pk[0] = (_Float16)av[i]; pk[1] = (_Float16)bv[i];
      *(half2v*)(smT + (r * 130 + px) * 4 + 2 * p2t) = pk;
    }
  }
  __syncthreads();

  // ---- barrier-free K loop: 9 taps x (6 x K32 + K16-tail) ----
  f32x4 acc[2][7];
#pragma unroll
  for (int i = 0; i < 2; ++i)
#pragma unroll
    for (int j = 0; j < 7; ++j) acc[i][j] = (f32x4){0.f, 0.f, 0.f, 0.f};

  const bool lz = (l4 == 0);
#pragma unroll 3
  for (int t = 0; t < 9; ++t) {
    const int ki = t / 3;
    const int kj = t - 3 * ki;
#pragma unroll
    for (int cg = 0; cg < 6; ++cg) {
      const int s4 = ((t * 6 + cg) * 4 + l4) * 448;
      half8 bf[7];
#pragma unroll
      for (int f = 0; f < 7; ++f)
        bf[f] = *(const half8*)(BpT + (size_t)(s4 + n_base + f * 16 + l15) * 8);
      half8 af[2];
#pragma unroll
      for (int mf = 0; mf < 2; ++mf) {
        const int px = m_base + mf * 16 + l15 + kj;
        const int bi = cg * 4 + l4;
        af[mf] = *(const half8*)(smA + (ki * 130 + px) * 192 +
                                 (((bi & 24) | ((bi & 7) ^ (px & 7))) << 3));
      }
#pragma unroll
      for (int mf = 0; mf < 2; ++mf)
#pragma unroll
        for (int f = 0; f < 7; ++f)
          acc[mf][f] = __builtin_amdgcn_mfma_f32_16x16x32_f16(af[mf], bf[f], acc[mf][f], 0, 0, 0);
    }
    // tail: ci 192..195 as a l4==0-masked K32 MFMA
    half8 aft[2];
#pragma unroll
    for (int mf = 0; mf < 2; ++mf) {
      const int px = m_base + mf * 16 + l15 + kj;
      const half4 tv = *(const half4*)(smT + (ki * 130 + px) * 4);
      half8 a = {0, 0, 0, 0, 0, 0, 0, 0};
      if (lz) { a[0] = tv[0]; a[1] = tv[1]; a[2] = tv[2]; a[3] = tv[3]; }
      aft[mf] = a;
    }
#pragma unroll
    for (int f = 0; f < 7; ++f) {
      const half4 wv = *(const half4*)(Bt + (size_t)(t * 448 + n_base + f * 16 + l15) * 4);
      half8 bb = {0, 0, 0, 0, 0, 0, 0, 0};
      if (lz) { bb[0] = wv[0]; bb[1] = wv[1]; bb[2] = wv[2]; bb[3] = wv[3]; }
#pragma unroll
      for (int mf = 0; mf < 2; ++mf)
        acc[mf][f] = __builtin_amdgcn_mfma_f32_16x16x32_f16(aft[mf], bb, acc[mf][f], 0, 0, 0);
    }
  }

  // ---- epilogue: bias + 10*tanh + flow-add -> off_pm; sigmoid -> mask_pm ----
  const int hw0 = h * Ww;
#pragma unroll
  for (int f = 0; f < 7; ++f) {
    const int n = n_base + f * 16 + l15;
    if (n >= COFF) continue;
    const float bias = b_off[n];
    const bool isOff = (n < 288);
    const float* fl = (n < 144) ? f1 : f2;
    const size_t fladd = (size_t)(b * 2 + ((n & 1) ^ 1)) * HW;
#pragma unroll
    for (int mf = 0; mf < 2; ++mf) {
#pragma unroll
      for (int rr = 0; rr < 4; ++rr) {
        const int m = m_base + mf * 16 + l4 * 4 + rr;
        const float v = acc[mf][f][rr] + bias;
        const int p = hw0 + m;
        if (isOff) {
          const float e = __expf(2.f * v);
          off_pm[((size_t)b * HW + p) * 288 + n] = 10.f * (1.f - 2.f / (e + 1.f)) + fl[fladd + p];
        } else {
          mask_pm[((size_t)b * HW + p) * 144 + (n - 288)] =
              (_Float16)(1.f / (1.f + __expf(-v)));
        }
      }
    }
  }
}

// ---------------- kernel 2: modulated deformable conv, 16 px/block, MFMA phase 2 ----------
__global__ __launch_bounds__(256) void k_deform2(
    const _Float16* __restrict__ featT, const float* __restrict__ off_pm,
    const _Float16* __restrict__ mask_pm, const _Float16* __restrict__ wH,
    const float* __restrict__ dcb, float* __restrict__ out) {
  __shared__ __align__(16) char smem[16 * 1160 * 2];   // 37120 B
  _Float16* sm = (_Float16*)smem;                      // sm[pix][1160]
  float* red = (float*)smem;                           // red[w][16][66] (aliased after sync)
  const int w0  = blockIdx.x * 16;
  const int h   = blockIdx.y;
  const int b   = blockIdx.z;
  const int tid = (int)threadIdx.x;
  const int lane = tid & 63, wid = tid >> 6;
  const int l15 = lane & 15, l4 = lane >> 4;

#pragma unroll 1
  for (int i = 0; i < 9; ++i) {
    const int p   = tid + i * 256;        // 0..2303
    const int pix = p / 144;
    const int r   = p - pix * 144;
    const int g   = r / 9;
    const int k   = r - g * 9;
    const int w   = w0 + pix;
    const int hw  = h * Ww + w;
    const float2 off = *(const float2*)(off_pm + ((size_t)b * HW + hw) * 288 + 2 * r);
    const float mk = (float)mask_pm[((size_t)b * HW + hw) * 144 + r];
    const int ki = (k >= 6) ? 2 : (k >= 3 ? 1 : 0);
    const int kj = k - 3 * ki;
    const float py = (float)(h - 1 + ki) + off.x;
    const float px = (float)(w - 1 + kj) + off.y;
    const float y0f = floorf(py), x0f = floorf(px);
    const int y0 = (int)y0f, x0 = (int)x0f;
    const float ly = py - y0f, lx = px - x0f;
    const float hy = 1.f - ly, hx = 1.f - lx;
    const int y1 = y0 + 1, x1 = x0 + 1;
    const bool vy0 = (unsigned)y0 < (unsigned)Hh, vy1 = (unsigned)y1 < (unsigned)Hh;
    const bool vx0 = (unsigned)x0 < (unsigned)Ww, vx1 = (unsigned)x1 < (unsigned)Ww;
    const float w00 = (vy0 && vx0) ? hy * hx : 0.f;
    const float w01 = (vy0 && vx1) ? hy * lx : 0.f;
    const float w10 = (vy1 && vx0) ? ly * hx : 0.f;
    const float w11 = (vy1 && vx1) ? ly * lx : 0.f;
    const int cy0 = min(max(y0, 0), Hh - 1), cy1 = min(max(y1, 0), Hh - 1);
    const int cx0 = min(max(x0, 0), Ww - 1), cx1 = min(max(x1, 0), Ww - 1);
    const _Float16* gbase = featT + ((size_t)(b * 16 + g) * HW) * 8;
    const half8 s00 = *(const half8*)(gbase + (cy0 * Ww + cx0) * 8);
    const half8 s01 = *(const half8*)(gbase + (cy0 * Ww + cx1) * 8);
    const half8 s10 = *(const half8*)(gbase + (cy1 * Ww + cx0) * 8);
    const half8 s11 = *(const half8*)(gbase + (cy1 * Ww + cx1) * 8);
    half8 v = s00 * splat8(w00) + s01 * splat8(w01) + s10 * splat8(w10) + s11 * splat8(w11);
    v = v * splat8(mk);
    const int swz = (g ^ (k & 7)) << 3;
    *(half8*)(sm + pix * 1160 + k * 128 + swz) = v;
  }
  __syncthreads();

  f32x4 acc[4];
#pragma unroll
  for (int nf = 0; nf < 4; ++nf) acc[nf] = (f32x4){0.f, 0.f, 0.f, 0.f};
#pragma unroll
  for (int j = 0; j < 9; ++j) {
    const int s  = wid * 9 + j;
    const int k  = s >> 2;
    const int cg = s & 3;
    const int gidx = cg * 4 + l4;
    const half8 af = *(const half8*)(sm + l15 * 1160 + k * 128 + ((gidx ^ (k & 7)) << 3));
    const int koff = s * 32 + l4 * 8;
#pragma unroll
    for (int nf = 0; nf < 4; ++nf) {
      const half8 bf = *(const half8*)(wH + (nf * 16 + l15) * 1152 + koff);
      acc[nf] = __builtin_amdgcn_mfma_f32_16x16x32_f16(af, bf, acc[nf], 0, 0, 0);
    }
  }
  __syncthreads();
#pragma unroll
  for (int nf = 0; nf < 4; ++nf)
#pragma unroll
    for (int rr = 0; rr < 4; ++rr)
      red[(wid * 16 + l4 * 4 + rr) * 66 + nf * 16 + l15] = acc[nf][rr];
  __syncthreads();

  const int m  = tid & 15;
  const int ng = tid >> 4;
#pragma unroll
  for (int i = 0; i < 4; ++i) {
    const int n = ng + 16 * i;
    float val = red[(0 * 16 + m) * 66 + n] + red[(1 * 16 + m) * 66 + n] +
                red[(2 * 16 + m) * 66 + n] + red[(3 * 16 + m) * 66 + n];
    out[(size_t)(b * 64 + n) * HW + h * Ww + w0 + m] = val + dcb[n];
  }
}

extern "C" void kernel_launch(void* const* d_in, const int* in_sizes, int n_in,
                              void* d_out, int out_size, void* d_ws, size_t ws_size,
                              hipStream_t stream) {
  const float* extra = (const float*)d_in[0];
  const float* f1    = (const float*)d_in[1];
  const float* f2    = (const float*)d_in[2];
  const float* fp    = (const float*)d_in[3];
  const float* fn2   = (const float*)d_in[4];
  const float* w_off = (const float*)d_in[5];
  const float* b_off = (const float*)d_in[6];
  const float* dcw   = (const float*)d_in[7];
  const float* dcb   = (const float*)d_in[8];
  float* out = (float*)d_out;

  // ws layout (~57.3 MB)
  float*    off_pm  = (float*)d_ws;                      // 2*HW*288 f32
  _Float16* mask_pm = (_Float16*)(off_pm + 2 * 288 * HW);// 2*HW*144 fp16
  _Float16* featT   = mask_pm + 2 * 144 * HW;            // 2*16*HW*8 fp16
  _Float16* BpT     = featT + 2 * 128 * HW;              // 774144 fp16
  _Float16* Bt      = BpT + 774144;                      // 16128 fp16
  _Float16* wH      = Bt + 16128;                        // 73728 fp16

  hipLaunchKernelGGL(k_prep_dcw, dim3(288), dim3(256), 0, stream, dcw, wH);
  hipLaunchKernelGGL(k_prep_w, dim3((774144 + 16128 + 255) / 256), dim3(256), 0, stream,
                     w_off, BpT, Bt);
  hipLaunchKernelGGL(k_prep_feat, dim3(128), dim3(256), 0, stream, fp, fn2, featT);
  hipLaunchKernelGGL(k_offconv_mfma, dim3(128, 2), dim3(1024), 0, stream,
                     extra, f1, f2, BpT, Bt, b_off, off_pm, mask_pm);
  hipLaunchKernelGGL(k_deform2, dim3(8, 128, 2), dim3(256), 0, stream,
                     featT, off_pm, mask_pm, wH, dcb, out);
}